// Round 1
// baseline (1797.643 us; speedup 1.0000x reference)
//
#include <hip/hip_runtime.h>

// ---------------------------------------------------------------------------
// MultiHeadAttention forward: B=4, L=2048, D=1024, H=16, dk=64
// Outputs: out [B,L,D] fp32  then  attn [B,H,L,L] fp32 (concatenated in d_out)
// Strategy: bf16 MFMA everywhere (threshold is bf16-scale), fp32 softmax/attn.
// ---------------------------------------------------------------------------

typedef __bf16 bf16_t;
typedef __bf16 bf16x8 __attribute__((ext_vector_type(8)));
typedef __bf16 bf16x4 __attribute__((ext_vector_type(4)));
typedef float  f32x4  __attribute__((ext_vector_type(4)));

#define LOG2E 1.4426950408889634f

// async global->LDS, 16B per lane. LDS base must be wave-uniform.
__device__ __forceinline__ void async16(const bf16_t* g, bf16_t* l) {
    __builtin_amdgcn_global_load_lds(
        (const __attribute__((address_space(1))) unsigned int*)g,
        (__attribute__((address_space(3))) unsigned int*)l,
        16, 0, 0);
}

// ---------------------------------------------------------------------------
// fp32 -> bf16 cast, 4 elems/thread. n = 8388608 -> grid 8192 x 256.
__global__ void cast_bf16(const float* __restrict__ src, bf16_t* __restrict__ dst) {
    size_t i = ((size_t)blockIdx.x * 256 + threadIdx.x) * 4;
    float4 v = *(const float4*)(src + i);
    bf16x4 o = { (bf16_t)v.x, (bf16_t)v.y, (bf16_t)v.z, (bf16_t)v.w };
    *(bf16x4*)(dst + i) = o;
}

// ---------------------------------------------------------------------------
// W [1024][1024] fp32 -> Wt [1024][1024] bf16 with Wt[n][k] = W[k][n]
__global__ void transpose_w(const float* __restrict__ W, bf16_t* __restrict__ Wt) {
    __shared__ bf16_t t[64][65];
    const int k0 = blockIdx.x * 64, n0 = blockIdx.y * 64;
    const int tr = threadIdx.x >> 6, tc = threadIdx.x & 63;
#pragma unroll
    for (int i = 0; i < 16; ++i) {
        int kk = i * 4 + tr;
        t[kk][tc] = (bf16_t)W[(size_t)(k0 + kk) * 1024 + n0 + tc];
    }
    __syncthreads();
#pragma unroll
    for (int i = 0; i < 16; ++i) {
        int nn = i * 4 + tr;
        Wt[(size_t)(n0 + nn) * 1024 + k0 + tc] = t[tc][nn];
    }
}

// ---------------------------------------------------------------------------
// Vb [B*L][1024] (head h cols h*64..) -> Vt [B][H][64][2048]
__global__ void transpose_v(const bf16_t* __restrict__ Vb, bf16_t* __restrict__ Vt) {
    __shared__ bf16_t t[64][65];
    const int l0 = blockIdx.x * 64, h = blockIdx.y, b = blockIdx.z;
    const int tr = threadIdx.x >> 6, tc = threadIdx.x & 63;
    const bf16_t* src = Vb + ((size_t)b * 2048) * 1024 + h * 64;
#pragma unroll
    for (int i = 0; i < 16; ++i) {
        int ll = i * 4 + tr;
        t[ll][tc] = src[(size_t)(l0 + ll) * 1024 + tc];
    }
    __syncthreads();
    bf16_t* dst = Vt + ((size_t)(b * 16 + h) * 64) * 2048;
#pragma unroll
    for (int i = 0; i < 16; ++i) {
        int dd = i * 4 + tr;
        dst[(size_t)dd * 2048 + l0 + tc] = t[tc][dd];
    }
}

// ---------------------------------------------------------------------------
// C[M=8192][N=1024] = alpha * (A[M][K=1024] @ Bt[N][K]^T + bias[N])
// m97-style: 128x128 tile, BK=32, 4 waves in 2x2, global_load_lds 16B.
template <typename OutT>
__global__ __launch_bounds__(256) void gemm_bt(const bf16_t* __restrict__ A,
                                               const bf16_t* __restrict__ Bt,
                                               const float* __restrict__ bias,
                                               OutT* __restrict__ C, float alpha) {
    constexpr int K = 1024, N = 1024;
    __shared__ __align__(16) bf16_t As[128 * 32];
    __shared__ __align__(16) bf16_t Bs[128 * 32];
    const int tid = threadIdx.x;
    const int wave = tid >> 6, lane = tid & 63;
    const int r = lane & 15, qd = lane >> 4;
    const size_t m0 = (size_t)blockIdx.x * 128;
    const int n0 = blockIdx.y * 128;
    const int wm = (wave >> 1) * 64, wn = (wave & 1) * 64;

    f32x4 acc[4][4] = {};

    for (int kt = 0; kt < K; kt += 32) {
        __syncthreads();
#pragma unroll
        for (int i = 0; i < 2; ++i) {
            int c = i * 256 + tid;
            int row = c >> 2, col = (c & 3) << 3;
            async16(A + (m0 + row) * K + kt + col, As + (size_t)(i * 256 + wave * 64) * 8);
            async16(Bt + (size_t)(n0 + row) * K + kt + col, Bs + (size_t)(i * 256 + wave * 64) * 8);
        }
        __syncthreads();
        bf16x8 af[4], bfr[4];
#pragma unroll
        for (int mb = 0; mb < 4; ++mb)
            af[mb] = *(const bf16x8*)(As + (wm + mb * 16 + r) * 32 + qd * 8);
#pragma unroll
        for (int nb = 0; nb < 4; ++nb)
            bfr[nb] = *(const bf16x8*)(Bs + (wn + nb * 16 + r) * 32 + qd * 8);
#pragma unroll
        for (int mb = 0; mb < 4; ++mb)
#pragma unroll
            for (int nb = 0; nb < 4; ++nb)
                acc[mb][nb] = __builtin_amdgcn_mfma_f32_16x16x32_bf16(af[mb], bfr[nb], acc[mb][nb], 0, 0, 0);
    }
    // epilogue: C/D layout col=lane&15, row=(lane>>4)*4+reg
#pragma unroll
    for (int mb = 0; mb < 4; ++mb) {
#pragma unroll
        for (int nb = 0; nb < 4; ++nb) {
            const int col = n0 + wn + nb * 16 + r;
            const float bv = bias[col];
            const size_t rowb = m0 + wm + mb * 16 + qd * 4;
#pragma unroll
            for (int rg = 0; rg < 4; ++rg) {
                float v = (acc[mb][nb][rg] + bv) * alpha;
                if constexpr (sizeof(OutT) == 2)
                    C[(rowb + rg) * N + col] = (bf16_t)v;
                else
                    C[(rowb + rg) * N + col] = v;
            }
        }
    }
}

// ---------------------------------------------------------------------------
// Fused attention for one (b, h, 64-row q-tile). Two passes over K chunks:
// pass1: exact online (m,l); pass2: recompute S, write attn fp32, PV via LDS.
__global__ __launch_bounds__(256) void attn_fused(const bf16_t* __restrict__ Qb,
                                                  const bf16_t* __restrict__ Kb,
                                                  const bf16_t* __restrict__ Vt,
                                                  float* __restrict__ attn_out,
                                                  bf16_t* __restrict__ ctx) {
    constexpr int L = 2048, Dm = 1024, H = 16;
    // pads chosen so b128 frag reads spread evenly over bank-quads
    __shared__ __align__(16) bf16_t Ks[128][72];
    __shared__ __align__(16) bf16_t Ps[64][136];
    __shared__ __align__(16) bf16_t Vs[64][136];

    const int tid = threadIdx.x;
    const int wave = tid >> 6, lane = tid & 63;
    const int r = lane & 15, qd = lane >> 4;
    const int q0 = blockIdx.x * 64;
    const int h = blockIdx.y, b = blockIdx.z;

    const bf16_t* Kbase = Kb + ((size_t)b * L) * Dm + h * 64;
    const bf16_t* Vbase = Vt + ((size_t)(b * H + h) * 64) * L;
    float* abase = attn_out + (size_t)(b * H + h) * L * L;

    // persistent Q fragments (Q pre-scaled by 1/8 in its projection GEMM)
    bf16x8 qf0, qf1;
    {
        const bf16_t* qp = Qb + ((size_t)b * L + q0 + wave * 16 + r) * Dm + h * 64 + qd * 8;
        qf0 = *(const bf16x8*)(qp);
        qf1 = *(const bf16x8*)(qp + 32);
    }

    float mrow[4], lrow[4];
#pragma unroll
    for (int i = 0; i < 4; ++i) { mrow[i] = -3.0e38f; lrow[i] = 0.f; }

    // ---- pass 1: exact (m, l) per q-row ----
    for (int ch = 0; ch < 16; ++ch) {
        const int kc = ch * 128;
        __syncthreads();
#pragma unroll
        for (int i = 0; i < 4; ++i) {
            int c = tid + 256 * i;
            int row = c >> 3, col = (c & 7) << 3;
            *(bf16x8*)(&Ks[row][col]) = *(const bf16x8*)(Kbase + (size_t)(kc + row) * Dm + col);
        }
        __syncthreads();
        f32x4 s[8];
#pragma unroll
        for (int nb = 0; nb < 8; ++nb) {
            bf16x8 b0 = *(const bf16x8*)(&Ks[nb * 16 + r][qd * 8]);
            bf16x8 b1 = *(const bf16x8*)(&Ks[nb * 16 + r][32 + qd * 8]);
            f32x4 a = {};
            a = __builtin_amdgcn_mfma_f32_16x16x32_bf16(qf0, b0, a, 0, 0, 0);
            a = __builtin_amdgcn_mfma_f32_16x16x32_bf16(qf1, b1, a, 0, 0, 0);
            s[nb] = a;
        }
#pragma unroll
        for (int rg = 0; rg < 4; ++rg) {
            float mx = s[0][rg];
#pragma unroll
            for (int nb = 1; nb < 8; ++nb) mx = fmaxf(mx, s[nb][rg]);
#pragma unroll
            for (int d = 1; d < 16; d <<= 1) mx = fmaxf(mx, __shfl_xor(mx, d, 64));
            const float mnew = fmaxf(mrow[rg], mx);
            float sm = 0.f;
#pragma unroll
            for (int nb = 0; nb < 8; ++nb) sm += exp2f((s[nb][rg] - mnew) * LOG2E);
#pragma unroll
            for (int d = 1; d < 16; d <<= 1) sm += __shfl_xor(sm, d, 64);
            lrow[rg] = lrow[rg] * exp2f((mrow[rg] - mnew) * LOG2E) + sm;
            mrow[rg] = mnew;
        }
    }
    float rln[4];
#pragma unroll
    for (int rg = 0; rg < 4; ++rg) rln[rg] = 1.f / lrow[rg];

    f32x4 cacc[4] = {};

    // ---- pass 2: recompute S, emit attn, accumulate ctx ----
    for (int ch = 0; ch < 16; ++ch) {
        const int kc = ch * 128;
        __syncthreads();
#pragma unroll
        for (int i = 0; i < 4; ++i) {
            int c = tid + 256 * i;
            int row = c >> 3, col = (c & 7) << 3;
            *(bf16x8*)(&Ks[row][col]) = *(const bf16x8*)(Kbase + (size_t)(kc + row) * Dm + col);
        }
#pragma unroll
        for (int i = 0; i < 4; ++i) {
            int c = tid + 256 * i;
            int row = c >> 4, col = (c & 15) << 3;
            *(bf16x8*)(&Vs[row][col]) = *(const bf16x8*)(Vbase + (size_t)row * L + kc + col);
        }
        __syncthreads();
#pragma unroll
        for (int nb = 0; nb < 8; ++nb) {
            bf16x8 b0 = *(const bf16x8*)(&Ks[nb * 16 + r][qd * 8]);
            bf16x8 b1 = *(const bf16x8*)(&Ks[nb * 16 + r][32 + qd * 8]);
            f32x4 a = {};
            a = __builtin_amdgcn_mfma_f32_16x16x32_bf16(qf0, b0, a, 0, 0, 0);
            a = __builtin_amdgcn_mfma_f32_16x16x32_bf16(qf1, b1, a, 0, 0, 0);
#pragma unroll
            for (int rg = 0; rg < 4; ++rg) {
                float p = exp2f((a[rg] - mrow[rg]) * LOG2E) * rln[rg];
                abase[(size_t)(q0 + wave * 16 + qd * 4 + rg) * L + kc + nb * 16 + r] = p;
                Ps[wave * 16 + qd * 4 + rg][nb * 16 + r] = (bf16_t)p;
            }
        }
        __syncthreads();  // P visible to all lanes of the wave (cross-lane via LDS)
#pragma unroll
        for (int kb = 0; kb < 4; ++kb) {
            bf16x8 pa = *(const bf16x8*)(&Ps[wave * 16 + r][kb * 32 + qd * 8]);
#pragma unroll
            for (int db = 0; db < 4; ++db) {
                bf16x8 vb = *(const bf16x8*)(&Vs[db * 16 + r][kb * 32 + qd * 8]);
                cacc[db] = __builtin_amdgcn_mfma_f32_16x16x32_bf16(pa, vb, cacc[db], 0, 0, 0);
            }
        }
    }
    // ctx [B*L][1024] bf16, head cols h*64..
#pragma unroll
    for (int db = 0; db < 4; ++db)
#pragma unroll
        for (int rg = 0; rg < 4; ++rg)
            ctx[((size_t)b * L + q0 + wave * 16 + qd * 4 + rg) * Dm + h * 64 + db * 16 + r] =
                (bf16_t)cacc[db][rg];
}

// ---------------------------------------------------------------------------
extern "C" void kernel_launch(void* const* d_in, const int* in_sizes, int n_in,
                              void* d_out, int out_size, void* d_ws, size_t ws_size,
                              hipStream_t stream) {
    const float* query = (const float*)d_in[0];
    const float* key_  = (const float*)d_in[1];
    const float* value = (const float*)d_in[2];
    const float* Wq = (const float*)d_in[3];
    const float* bq = (const float*)d_in[4];
    const float* Wk = (const float*)d_in[5];
    const float* bk = (const float*)d_in[6];
    const float* Wv = (const float*)d_in[7];
    const float* bv = (const float*)d_in[8];
    const float* Wo = (const float*)d_in[9];
    const float* bo = (const float*)d_in[10];

    float* out  = (float*)d_out;
    float* attn = out + (size_t)8192 * 1024;

    char* ws = (char*)d_ws;
    bf16_t* Xb  = (bf16_t*)(ws);                              // 16 MB (also reused as ctx)
    bf16_t* Wtb = (bf16_t*)(ws + (size_t)16 * 1024 * 1024);   // 8 MB (4 transposed weights)
    bf16_t* Qb  = (bf16_t*)(ws + (size_t)24 * 1024 * 1024);   // 16 MB
    bf16_t* Kb  = (bf16_t*)(ws + (size_t)40 * 1024 * 1024);   // 16 MB
    bf16_t* Vb  = (bf16_t*)(ws + (size_t)56 * 1024 * 1024);   // 16 MB
    bf16_t* Vt  = (bf16_t*)(ws + (size_t)72 * 1024 * 1024);   // 16 MB  (total 88 MB)
    bf16_t* ctx = Xb;  // query cast is dead after Q-GEMM chain

    dim3 b256(256);

    transpose_w<<<dim3(16, 16), b256, 0, stream>>>(Wq, Wtb + (size_t)0 * 1048576);
    transpose_w<<<dim3(16, 16), b256, 0, stream>>>(Wk, Wtb + (size_t)1 * 1048576);
    transpose_w<<<dim3(16, 16), b256, 0, stream>>>(Wv, Wtb + (size_t)2 * 1048576);
    transpose_w<<<dim3(16, 16), b256, 0, stream>>>(Wo, Wtb + (size_t)3 * 1048576);

    cast_bf16<<<8192, b256, 0, stream>>>(query, Xb);
    gemm_bt<bf16_t><<<dim3(64, 8), b256, 0, stream>>>(Xb, Wtb + (size_t)0 * 1048576, bq, Qb, 0.125f);
    cast_bf16<<<8192, b256, 0, stream>>>(key_, Xb);
    gemm_bt<bf16_t><<<dim3(64, 8), b256, 0, stream>>>(Xb, Wtb + (size_t)1 * 1048576, bk, Kb, 1.0f);
    cast_bf16<<<8192, b256, 0, stream>>>(value, Xb);
    gemm_bt<bf16_t><<<dim3(64, 8), b256, 0, stream>>>(Xb, Wtb + (size_t)2 * 1048576, bv, Vb, 1.0f);

    transpose_v<<<dim3(32, 16, 4), b256, 0, stream>>>(Vb, Vt);

    attn_fused<<<dim3(32, 16, 4), b256, 0, stream>>>(Qb, Kb, Vt, attn, ctx);

    gemm_bt<float><<<dim3(64, 8), b256, 0, stream>>>(ctx, Wtb + (size_t)3 * 1048576, bo, out, 1.0f);
}